// Round 6
// baseline (592.214 us; speedup 1.0000x reference)
//
#include <hip/hip_runtime.h>
#include <math.h>

typedef __attribute__((ext_vector_type(8))) short short8;
typedef __attribute__((ext_vector_type(4))) float f32x4;
typedef __attribute__((ext_vector_type(4))) unsigned short us4;
typedef __attribute__((ext_vector_type(4))) float fl4;

#define B_ 2
#define S_ 2048
#define H_ 16
#define D_ 128
#define HID 2048

__device__ __forceinline__ unsigned short f2bf(float f){
  unsigned u = __builtin_bit_cast(unsigned, f);
  u += 0x7fffu + ((u >> 16) & 1u);
  return (unsigned short)(u >> 16);
}
__device__ __forceinline__ float bf2f(unsigned short u){
  unsigned x = ((unsigned)u) << 16;
  return __builtin_bit_cast(float, x);
}
__device__ __forceinline__ int cvtpk(float lo, float hi){
  int r; asm("v_cvt_pk_bf16_f32 %0, %1, %2" : "=v"(r) : "v"(lo), "v"(hi)); return r;
}

// async global -> LDS, 16 bytes per lane (dest must be linear: base + lane*16)
__device__ __forceinline__ void g2lds16(const unsigned short* g, unsigned short* l){
  __builtin_amdgcn_global_load_lds(
      (const __attribute__((address_space(1))) unsigned int*)g,
      (__attribute__((address_space(3))) unsigned int*)l, 16, 0, 0);
}

// ---------- f32 -> bf16 convert ----------
__global__ void cvt_k(const float* __restrict__ src, unsigned short* __restrict__ dst){
  int i = (blockIdx.x * 256 + threadIdx.x) * 4;
  fl4 v = *(const fl4*)(src + i);
  us4 o;
  #pragma unroll
  for (int t = 0; t < 4; t++) o[t] = f2bf(v[t]);
  *(us4*)(dst + i) = o;
}

// ---------- cos/sin tables ----------
__global__ void tab_k(const float* __restrict__ freqs, float* __restrict__ ctab,
                      float* __restrict__ stab){
  int i = blockIdx.x * 256 + threadIdx.x;
  float f = freqs[i];
  ctab[i] = cosf(f);
  stab[i] = sinf(f);
}

// ---------- GEMM: C[i][j] = sum_k A[i][k] * B[j][k]  (2-phase dbuf, XCD-grouped) ----------
// EPI==1: grid 1024 (bx32,by16,z2) -> Q/K scatter [B,H,S,D]; grouped by bx per XCD (A reuse)
// EPI==2: grid 512  (bx16,by32) A=Wv,B=x -> V^T [B,H,D,S]; grouped by bx (Wv reuse)
// EPI==0: grid 512  (bx32,by16) -> f32 Of; grouped by by (Wo reuse)
template<int EPI>
__global__ __launch_bounds__(256) void gemm_k(
    const unsigned short* __restrict__ A,
    const unsigned short* __restrict__ B0,
    const unsigned short* __restrict__ B1,
    unsigned short* __restrict__ O0,
    unsigned short* __restrict__ O1,
    float* __restrict__ Of)
{
  __shared__ __align__(16) unsigned short As[2][128 * 32];
  __shared__ __align__(16) unsigned short Bs[2][128 * 32];
  const int tid = threadIdx.x;
  const int l = tid & 63, lg = l >> 4, lr = l & 15;
  const int w = tid >> 6, wm = w & 1, wn = w >> 1;

  // XCD-aware bijective remap (grid % 8 == 0): contiguous work chunk per XCD
  const int f = blockIdx.x;
  int bx, by, z = 0;
  if (EPI == 1){ int g = (f & 7) * 128 + (f >> 3); bx = g >> 5; int r = g & 31; by = r & 15; z = r >> 4; }
  else if (EPI == 2){ int g = (f & 7) * 64 + (f >> 3); bx = g >> 5; by = g & 31; }
  else { int g = (f & 7) * 64 + (f >> 3); by = g >> 5; bx = g & 31; }
  const int m0 = bx * 128, n0 = by * 128;
  const unsigned short* Bm = (EPI == 1 && z == 1) ? B1 : B0;

  f32x4 acc[4][4];
  #pragma unroll
  for (int i = 0; i < 4; i++)
    #pragma unroll
    for (int j = 0; j < 4; j++)
      acc[i][j] = f32x4{0.f, 0.f, 0.f, 0.f};

  const unsigned short* gA = A  + (size_t)(m0 + (tid >> 2)) * HID + (tid & 3) * 8;
  const unsigned short* gB = Bm + (size_t)(n0 + (tid >> 2)) * HID + (tid & 3) * 8;

  #define GSTAGE(buf, kt) do {                                   \
    g2lds16(gA + (kt),            As[buf] + tid * 8);            \
    g2lds16(gA + 64 * HID + (kt), As[buf] + 2048 + tid * 8);     \
    g2lds16(gB + (kt),            Bs[buf] + tid * 8);            \
    g2lds16(gB + 64 * HID + (kt), Bs[buf] + 2048 + tid * 8);     \
  } while (0)

  GSTAGE(0, 0);
  __syncthreads();
  int cur = 0;
  for (int t = 0; t < 64; t++){
    if (t < 63) GSTAGE(cur ^ 1, (t + 1) * 32);
    short8 aF[4], bF[4];
    #pragma unroll
    for (int mi = 0; mi < 4; mi++)
      aF[mi] = *(const short8*)(As[cur] + (wm * 64 + mi * 16 + lr) * 32 + lg * 8);
    #pragma unroll
    for (int ni = 0; ni < 4; ni++)
      bF[ni] = *(const short8*)(Bs[cur] + (wn * 64 + ni * 16 + lr) * 32 + lg * 8);
    #pragma unroll
    for (int mi = 0; mi < 4; mi++)
      #pragma unroll
      for (int ni = 0; ni < 4; ni++)
        acc[mi][ni] = __builtin_amdgcn_mfma_f32_16x16x32_bf16(aF[mi], bF[ni], acc[mi][ni], 0, 0, 0);
    __syncthreads();
    cur ^= 1;
  }
  #undef GSTAGE

  if (EPI == 1){
    unsigned short* O = z ? O1 : O0;
    #pragma unroll
    for (int mi = 0; mi < 4; mi++)
      #pragma unroll
      for (int r = 0; r < 4; r++){
        int i = m0 + wm * 64 + mi * 16 + lg * 4 + r;
        int b = i >> 11, s = i & 2047;
        #pragma unroll
        for (int ni = 0; ni < 4; ni++){
          int j = n0 + wn * 64 + ni * 16 + lr;
          int h = j >> 7, d = j & 127;
          O[((size_t)(b * H_ + h) * S_ + s) * D_ + d] = f2bf(acc[mi][ni][r]);
        }
      }
  } else if (EPI == 2){
    #pragma unroll
    for (int mi = 0; mi < 4; mi++)
      #pragma unroll
      for (int r = 0; r < 4; r++){
        int gi = m0 + wm * 64 + mi * 16 + lg * 4 + r;   // feature
        int h = gi >> 7, d = gi & 127;
        #pragma unroll
        for (int ni = 0; ni < 4; ni++){
          int gj = n0 + wn * 64 + ni * 16 + lr;         // token
          int b = gj >> 11, s = gj & 2047;
          O0[((size_t)(b * H_ + h) * D_ + d) * S_ + s] = f2bf(acc[mi][ni][r]);
        }
      }
  } else {
    #pragma unroll
    for (int mi = 0; mi < 4; mi++)
      #pragma unroll
      for (int r = 0; r < 4; r++){
        int i = m0 + wm * 64 + mi * 16 + lg * 4 + r;
        #pragma unroll
        for (int ni = 0; ni < 4; ni++){
          int j = n0 + wn * 64 + ni * 16 + lr;
          Of[(size_t)i * HID + j] = acc[mi][ni][r];
        }
      }
  }
}

// ---------- in-place RoPE on Q and K ----------
__global__ void rope_k(unsigned short* __restrict__ Q, unsigned short* __restrict__ K,
                       const float* __restrict__ ctab, const float* __restrict__ stab){
  int idx = blockIdx.x * 256 + threadIdx.x;
  unsigned short* P = (idx >= (1 << 20)) ? K : Q;
  int e  = idx & ((1 << 20) - 1);
  int g  = e & 15;
  int s  = (e >> 4) & 2047;
  int bh = e >> 15;
  int d0 = g * 4;
  size_t base = ((size_t)bh * S_ + s) * D_;
  us4 qa = *(us4*)(P + base + d0);
  us4 qb = *(us4*)(P + base + d0 + 64);
  fl4 ca = *(const fl4*)(ctab + s * D_ + d0);
  fl4 sa = *(const fl4*)(stab + s * D_ + d0);
  fl4 cb = *(const fl4*)(ctab + s * D_ + d0 + 64);
  fl4 sb = *(const fl4*)(stab + s * D_ + d0 + 64);
  us4 oa, ob;
  #pragma unroll
  for (int t = 0; t < 4; t++){
    float xa = bf2f(qa[t]), xb = bf2f(qb[t]);
    oa[t] = f2bf(xa * ca[t] - xb * sa[t]);
    ob[t] = f2bf(xb * cb[t] + xa * sb[t]);
  }
  *(us4*)(P + base + d0)      = oa;
  *(us4*)(P + base + d0 + 64) = ob;
}

// ---------- flash attention: 8 waves, QBLK=128, dbuf g2lds, XCD-grouped ----------
__global__ __launch_bounds__(512) void attn_k(
    const unsigned short* __restrict__ Q,     // [B,H,S,D] (rope'd)
    const unsigned short* __restrict__ Kg,    // [B,H,S,D] (rope'd)
    const unsigned short* __restrict__ Vt,    // [B,H,D,S]
    const float* __restrict__ mask,           // [S,S]
    const float* __restrict__ alibi,          // [H,S]
    unsigned short* __restrict__ Ctx)         // [B,S,H,D]
{
  __shared__ __align__(16) unsigned short Kl[2][64 * 128];  // 32 KB
  __shared__ __align__(16) unsigned short Vl[2][128 * 64];  // 32 KB
  const int tid = threadIdx.x;
  const int l = tid & 63, lg = l >> 4, lr = l & 15;
  const int w = tid >> 6;                                   // 0..7
  // XCD-grouped: 64 blocks (4 bh) per XCD -> K/V L2-resident
  const int f = blockIdx.x;
  const int g = (f & 7) * 64 + (f >> 3);
  const int bh = g >> 4, qx = g & 15;
  const int b = bh >> 4, h = bh & 15;
  const int q0 = qx * 128 + w * 16;
  const size_t hb = (size_t)bh * S_ * D_;
  const float* mrow = mask + (size_t)(q0 + lr) * S_;
  const float* al = alibi + h * S_;
  const int sidx = (l & 48) + ((l & 48) >> 2);
  const float SCL2E = 0.08838834764831845f * 1.4426950408889634f;
  const float L2E = 1.4426950408889634f;

  // staging: pre-swizzled GLOBAL src, LINEAR LDS dest. 512 threads:
  // K tile [64][128]: 16 granules/row; thread -> row=tid>>4, slot=tid&15
  const unsigned short* gK = Kg + hb + (size_t)(tid >> 4) * D_
                             + (((tid & 15) ^ ((tid >> 4) & 7)) * 8);
  // V^T tile [128][64]: 8 granules/row; thread -> row=tid>>3, slot=tid&7
  const unsigned short* gV = Vt + hb + (size_t)(tid >> 3) * S_
                             + (((tid & 7) ^ ((tid >> 3) & 7)) * 8);

  #define ASTAGE(buf, kv)  do {                                            \
    g2lds16(gK + (size_t)(kv) * D_,        Kl[buf] + tid * 8);             \
    g2lds16(gK + (size_t)((kv) + 32) * D_, Kl[buf] + 4096 + tid * 8);      \
    g2lds16(gV + (kv),                     Vl[buf] + tid * 8);             \
    g2lds16(gV + 64 * S_ + (kv),           Vl[buf] + 4096 + tid * 8);      \
  } while (0)

  int koff[4];
  #pragma unroll
  for (int c = 0; c < 4; c++) koff[c] = ((c * 4 + lg) ^ (lr & 7)) * 8;
  const int vo0 = (lg ^ (lr & 7)) * 8, vo1 = ((4 + lg) ^ (lr & 7)) * 8;

  short8 qf[4];
  #pragma unroll
  for (int c = 0; c < 4; c++)
    qf[c] = *(const short8*)(Q + hb + (size_t)(q0 + lr) * D_ + c * 32 + lg * 8);

  f32x4 acc[8];
  #pragma unroll
  for (int c = 0; c < 8; c++) acc[c] = f32x4{0.f, 0.f, 0.f, 0.f};
  float mr = -1e30f, lsum = 0.f;

  ASTAGE(0, 0);
  __syncthreads();
  int cur = 0;

  for (int t = 0; t < 32; t++){
    const int kv0 = t * 64;
    if (t < 31) ASTAGE(cur ^ 1, kv0 + 64);

    fl4 mk[4], aa[4];
    #pragma unroll
    for (int g2 = 0; g2 < 4; g2++){
      mk[g2] = *(const fl4*)(mrow + kv0 + g2 * 16 + 4 * lg);
      aa[g2] = *(const fl4*)(al  + kv0 + g2 * 16 + 4 * lg);
    }

    f32x4 sg[4];
    #pragma unroll
    for (int g2 = 0; g2 < 4; g2++) sg[g2] = f32x4{0.f, 0.f, 0.f, 0.f};
    #pragma unroll
    for (int g2 = 0; g2 < 4; g2++){
      const int row = g2 * 16 + lr;
      #pragma unroll
      for (int c = 0; c < 4; c++){
        short8 kf = *(const short8*)(Kl[cur] + row * 128 + koff[c]);
        sg[g2] = __builtin_amdgcn_mfma_f32_16x16x32_bf16(kf, qf[c], sg[g2], 0, 0, 0);
      }
    }

    float x[4][4];
    #pragma unroll
    for (int g2 = 0; g2 < 4; g2++)
      #pragma unroll
      for (int r = 0; r < 4; r++)
        x[g2][r] = fmaf(sg[g2][r], SCL2E, (mk[g2][r] + aa[g2][r]) * L2E);

    float mx = -1e30f;
    #pragma unroll
    for (int g2 = 0; g2 < 4; g2++)
      #pragma unroll
      for (int r = 0; r < 4; r++) mx = fmaxf(mx, x[g2][r]);

    float p[4][4], ps = 0.f;
    if (__all(mx <= mr + 8.f)){
      #pragma unroll
      for (int g2 = 0; g2 < 4; g2++)
        #pragma unroll
        for (int r = 0; r < 4; r++){
          p[g2][r] = exp2f(x[g2][r] - mr);
          ps += p[g2][r];
        }
      ps += __shfl_xor(ps, 16);
      ps += __shfl_xor(ps, 32);
      lsum += ps;
    } else {
      mx = fmaxf(mx, __shfl_xor(mx, 16));
      mx = fmaxf(mx, __shfl_xor(mx, 32));
      float mnew = fmaxf(mr, mx);
      float alpha = exp2f(mr - mnew);
      #pragma unroll
      for (int g2 = 0; g2 < 4; g2++)
        #pragma unroll
        for (int r = 0; r < 4; r++){
          p[g2][r] = exp2f(x[g2][r] - mnew);
          ps += p[g2][r];
        }
      ps += __shfl_xor(ps, 16);
      ps += __shfl_xor(ps, 32);
      lsum = lsum * alpha + ps;
      mr = mnew;
      float ar[4];
      #pragma unroll
      for (int r = 0; r < 4; r++) ar[r] = __shfl(alpha, sidx + r);
      #pragma unroll
      for (int c = 0; c < 8; c++)
        #pragma unroll
        for (int r = 0; r < 4; r++) acc[c][r] *= ar[r];
    }

    int pk0[4], pk1[4];
    #pragma unroll
    for (int r = 0; r < 4; r++){
      pk0[r] = cvtpk(p[0][r], p[1][r]);
      pk1[r] = cvtpk(p[2][r], p[3][r]);
    }

    const int srcb = lr + ((lg & 1) << 5);
    short8 af0, af1;
    #pragma unroll
    for (int j = 0; j < 8; j++){
      int w0 = __shfl(pk0[j & 3], srcb + ((j >> 2) << 4));
      int w1 = __shfl(pk1[j & 3], srcb + ((j >> 2) << 4));
      af0[j] = (short)((l & 32) ? ((unsigned)w0 >> 16) : ((unsigned)w0 & 0xffffu));
      af1[j] = (short)((l & 32) ? ((unsigned)w1 >> 16) : ((unsigned)w1 & 0xffffu));
    }

    #pragma unroll
    for (int c = 0; c < 8; c++){
      const int d0 = c * 16 + lr;
      short8 vf0 = *(const short8*)(Vl[cur] + d0 * 64 + vo0);
      short8 vf1 = *(const short8*)(Vl[cur] + d0 * 64 + vo1);
      acc[c] = __builtin_amdgcn_mfma_f32_16x16x32_bf16(af0, vf0, acc[c], 0, 0, 0);
      acc[c] = __builtin_amdgcn_mfma_f32_16x16x32_bf16(af1, vf1, acc[c], 0, 0, 0);
    }

    __syncthreads();
    cur ^= 1;
  }
  #undef ASTAGE

  float inv = 1.f / lsum;
  float ir[4];
  #pragma unroll
  for (int r = 0; r < 4; r++) ir[r] = __shfl(inv, sidx + r);
  #pragma unroll
  for (int r = 0; r < 4; r++){
    const int qg = q0 + 4 * lg + r;
    const size_t ob = ((size_t)(b * S_ + qg) * H_ + h) * D_;
    #pragma unroll
    for (int c = 0; c < 8; c++)
      Ctx[ob + c * 16 + lr] = f2bf(acc[c][r] * ir[r]);
  }
}

extern "C" void kernel_launch(void* const* d_in, const int* in_sizes, int n_in,
                              void* d_out, int out_size, void* d_ws, size_t ws_size,
                              hipStream_t stream){
  const float* x     = (const float*)d_in[0];
  const float* mask  = (const float*)d_in[1];
  const float* alibi = (const float*)d_in[2];
  const float* freqs = (const float*)d_in[3];
  const float* Wq    = (const float*)d_in[4];
  const float* Wk    = (const float*)d_in[5];
  const float* Wv    = (const float*)d_in[6];
  const float* Wo    = (const float*)d_in[7];
  float* out = (float*)d_out;

  unsigned short* ws  = (unsigned short*)d_ws;
  unsigned short* xb  = ws;
  unsigned short* wqb = ws + 8388608;
  unsigned short* wkb = ws + 12582912;
  unsigned short* wvb = ws + 16777216;
  unsigned short* wob = ws + 20971520;
  unsigned short* Qb  = ws + 25165824;
  unsigned short* Kb  = ws + 33554432;
  unsigned short* Vb  = ws + 41943040;         // V^T [B,H,D,S]
  unsigned short* ctx = xb;
  float* ctab = (float*)(ws + 50331648);
  float* stab = ctab + 262144;

  cvt_k<<<8192, 256, 0, stream>>>(x,  xb);
  cvt_k<<<4096, 256, 0, stream>>>(Wq, wqb);
  cvt_k<<<4096, 256, 0, stream>>>(Wk, wkb);
  cvt_k<<<4096, 256, 0, stream>>>(Wv, wvb);
  cvt_k<<<4096, 256, 0, stream>>>(Wo, wob);
  tab_k<<<1024, 256, 0, stream>>>(freqs, ctab, stab);

  gemm_k<1><<<1024, 256, 0, stream>>>(xb, wqb, wkb, Qb, Kb, nullptr);
  gemm_k<2><<<512, 256, 0, stream>>>(wvb, xb, nullptr, Vb, nullptr, nullptr);
  rope_k<<<8192, 256, 0, stream>>>(Qb, Kb, ctab, stab);
  attn_k<<<512, 512, 0, stream>>>(Qb, Kb, Vb, mask, alibi, ctx);
  gemm_k<0><<<512, 256, 0, stream>>>(ctx, wob, nullptr, nullptr, nullptr, out);
}

// Round 8
// 508.733 us; speedup vs baseline: 1.1641x; 1.1641x over previous
//
#include <hip/hip_runtime.h>
#include <math.h>

typedef __attribute__((ext_vector_type(8))) short short8;
typedef __attribute__((ext_vector_type(4))) float f32x4;
typedef __attribute__((ext_vector_type(4))) unsigned short us4;
typedef __attribute__((ext_vector_type(4))) float fl4;

#define B_ 2
#define S_ 2048
#define H_ 16
#define D_ 128
#define HID 2048

__device__ __forceinline__ unsigned short f2bf(float f){
  unsigned u = __builtin_bit_cast(unsigned, f);
  u += 0x7fffu + ((u >> 16) & 1u);
  return (unsigned short)(u >> 16);
}
__device__ __forceinline__ float bf2f(unsigned short u){
  unsigned x = ((unsigned)u) << 16;
  return __builtin_bit_cast(float, x);
}
__device__ __forceinline__ int cvtpk(float lo, float hi){
  int r; asm("v_cvt_pk_bf16_f32 %0, %1, %2" : "=v"(r) : "v"(lo), "v"(hi)); return r;
}

// async global -> LDS, 16 bytes per lane (dest linear: base + lane*16)
__device__ __forceinline__ void g2lds16(const unsigned short* g, unsigned short* l){
  __builtin_amdgcn_global_load_lds(
      (const __attribute__((address_space(1))) unsigned int*)g,
      (__attribute__((address_space(3))) unsigned int*)l, 16, 0, 0);
}

// ---------- f32 -> bf16 convert ----------
__global__ void cvt_k(const float* __restrict__ src, unsigned short* __restrict__ dst){
  int i = (blockIdx.x * 256 + threadIdx.x) * 4;
  fl4 v = *(const fl4*)(src + i);
  us4 o;
  #pragma unroll
  for (int t = 0; t < 4; t++) o[t] = f2bf(v[t]);
  *(us4*)(dst + i) = o;
}

// ---------- cos/sin tables ----------
__global__ void tab_k(const float* __restrict__ freqs, float* __restrict__ ctab,
                      float* __restrict__ stab){
  int i = blockIdx.x * 256 + threadIdx.x;
  float f = freqs[i];
  ctab[i] = cosf(f);
  stab[i] = sinf(f);
}

// ================= 256x256 8-phase GEMM (T2+T3+T4+T5) =================
// C[i][j] = sum_k A[i][k] * B[j][k], BK=64, 32 K-tiles, 8 waves (2M x 4N).
// LDS: 2 slots x 4 halves(A0,A1,B0,B1) x [128][64] bf16, XOR-granule swizzle.
// Each STG stages one 128-row half: rows r..r+63 then r+64..r+127 (+64*HID).
// vmcnt(6) at end of ph1,2,4,5,6,8: every half lands >=1 phase before its read.
#define PHEND_VM  do { asm volatile("s_waitcnt vmcnt(6)" ::: "memory"); \
  __builtin_amdgcn_sched_barrier(0); __builtin_amdgcn_s_barrier(); } while(0)
#define PHEND     do { \
  __builtin_amdgcn_sched_barrier(0); __builtin_amdgcn_s_barrier(); } while(0)
#define PREBAR    __builtin_amdgcn_s_barrier()

#define RD_A(slotb, half) do { _Pragma("unroll") \
  for (int i = 0; i < 4; i++){ _Pragma("unroll") \
    for (int ks = 0; ks < 2; ks++) \
      a[i][ks] = *(const short8*)(L + (slotb) + (half)*8192 + abase + i*2048 + kg[ks]); } } while(0)

#define RD_B(slotb, half) do { _Pragma("unroll") \
  for (int n = 0; n < 2; n++){ _Pragma("unroll") \
    for (int ks = 0; ks < 2; ks++) \
      b[(half)*2+n][ks] = *(const short8*)(L + (slotb) + 16384 + (half)*8192 + bbase + n*4096 + kg[ks]); } } while(0)

#define MMQ(X, Y) do { __builtin_amdgcn_s_setprio(1); _Pragma("unroll") \
  for (int i = 0; i < 4; i++){ _Pragma("unroll") \
    for (int n = 0; n < 2; n++){ _Pragma("unroll") \
      for (int ks = 0; ks < 2; ks++) \
        acc[(X)*4+i][(Y)*2+n] = __builtin_amdgcn_mfma_f32_16x16x32_bf16( \
            a[i][ks], b[(Y)*2+n][ks], acc[(X)*4+i][(Y)*2+n], 0, 0, 0); } } \
  __builtin_amdgcn_s_setprio(0); } while(0)

template<int EPI>   // 1: QKV (z selects Wq/Wk/Wv; z=2 writes V^T), 0: f32 out
__global__ __launch_bounds__(512, 2) void gemm8_k(
    const unsigned short* __restrict__ A,
    const unsigned short* __restrict__ W0,
    const unsigned short* __restrict__ W1,
    const unsigned short* __restrict__ W2,
    unsigned short* __restrict__ O0,
    unsigned short* __restrict__ O1,
    unsigned short* __restrict__ O2,
    float* __restrict__ Of)
{
  __shared__ __align__(16) unsigned short L[2 * 4 * 8192];   // 128 KiB
  const int tid = threadIdx.x;
  const int l = tid & 63, lg = l >> 4, lr = l & 15;
  const int w = tid >> 6, wm = w >> 2, wn = w & 3;
  const int m0 = blockIdx.x * 256, n0 = blockIdx.y * 256;
  const int z = (EPI == 1) ? blockIdx.z : 0;
  const unsigned short* Bop = (EPI == 1) ? (z == 0 ? W0 : (z == 1 ? W1 : W2)) : W0;

  f32x4 acc[8][4];
  #pragma unroll
  for (int i = 0; i < 8; i++)
    #pragma unroll
    for (int j = 0; j < 4; j++)
      acc[i][j] = f32x4{0.f, 0.f, 0.f, 0.f};

  // staging: linear LDS dest, pre-swizzled global source (granule^row&7)
  const int gsw = (((tid & 7) ^ ((tid >> 3) & 7)) * 8);
  const unsigned short* gA = A   + (size_t)(m0 + (tid >> 3)) * HID + gsw;
  const unsigned short* gB = Bop + (size_t)(n0 + (tid >> 3)) * HID + gsw;
  const size_t HIN = (size_t)64  * HID;   // second 64 rows within a half
  const size_t HB  = (size_t)128 * HID;   // half-1 base (+128 rows)

  // swizzled read offsets (row&7 == lr&7 for every fragment row)
  const int abase = (wm * 16 + lr) * 64;
  const int bbase = (wn * 16 + lr) * 64;
  int kg[2];
  kg[0] = ((lg)     ^ (lr & 7)) * 8;
  kg[1] = ((4 + lg) ^ (lr & 7)) * 8;

  #define STG(gsrc, tile, ldst) do { \
    const unsigned short* _s = (gsrc) + (size_t)(tile) * 64; \
    g2lds16(_s,       (ldst) + tid * 8); \
    g2lds16(_s + HIN, (ldst) + 4096 + tid * 8); } while(0)

  short8 a[4][2], b[4][2];

  // prologue: tile0 all halves -> slot0, drain, then A0(t1) -> slot1
  STG(gA, 0, L);                 // A0
  STG(gA + HB, 0, L + 8192);     // A1
  STG(gB, 0, L + 16384);         // B0
  STG(gB + HB, 0, L + 24576);    // B1
  asm volatile("s_waitcnt vmcnt(0)" ::: "memory");
  __builtin_amdgcn_sched_barrier(0);
  __builtin_amdgcn_s_barrier();
  STG(gA, 1, L + 32768);         // A0(t1) -> slot1

  for (int it = 0; it < 16; ++it){
    const int t1 = 2 * it + 1, t2 = 2 * it + 2, t3 = 2 * it + 3;
    // ph1: rd A0,B0 slot0 | stg B0(t1)
    RD_A(0, 0); RD_B(0, 0);
    STG(gB, t1, L + 32768 + 16384);
    PREBAR; MMQ(0, 0); PHEND_VM;
    // ph2: rd B1 slot0 | stg B1(t1)
    RD_B(0, 1);
    STG(gB + HB, t1, L + 32768 + 24576);
    PREBAR; MMQ(0, 1); PHEND_VM;
    // ph3: rd A1 slot0 | stg A1(t1)
    RD_A(0, 1);
    STG(gA + HB, t1, L + 32768 + 8192);
    PREBAR; MMQ(1, 0); PHEND;
    // ph4: stg A0(t2) -> slot0
    STG(gA, t2, L);
    PREBAR; MMQ(1, 1); PHEND_VM;
    // ph5: rd A0,B0 slot1 | stg B0(t2)
    RD_A(32768, 0); RD_B(32768, 0);
    STG(gB, t2, L + 16384);
    PREBAR; MMQ(0, 0); PHEND_VM;
    // ph6: rd B1 slot1 | stg B1(t2)
    RD_B(32768, 1);
    STG(gB + HB, t2, L + 24576);
    PREBAR; MMQ(0, 1); PHEND_VM;
    // ph7: rd A1 slot1 | stg A1(t2)
    RD_A(32768, 1);
    STG(gA + HB, t2, L + 8192);
    PREBAR; MMQ(1, 0); PHEND;
    // ph8: stg A0(t3) -> slot1
    STG(gA, t3, L + 32768);
    PREBAR; MMQ(1, 1); PHEND_VM;
  }
  #undef STG

  // epilogue
  #pragma unroll
  for (int mf = 0; mf < 8; mf++)
    #pragma unroll
    for (int nf = 0; nf < 4; nf++){
      const int j = n0 + nf * 64 + wn * 16 + lr;
      const int i0 = m0 + mf * 32 + wm * 16 + lg * 4;
      if (EPI == 0){
        #pragma unroll
        for (int r = 0; r < 4; r++)
          Of[(size_t)(i0 + r) * HID + j] = acc[mf][nf][r];
      } else if (z == 2){
        const int b = i0 >> 11, s = i0 & 2047, h = j >> 7, d = j & 127;
        us4 v;
        #pragma unroll
        for (int r = 0; r < 4; r++) v[r] = f2bf(acc[mf][nf][r]);
        *(us4*)(O2 + ((size_t)(b * H_ + h) * D_ + d) * S_ + s) = v;
      } else {
        unsigned short* O = z ? O1 : O0;
        const int h = j >> 7, d = j & 127;
        #pragma unroll
        for (int r = 0; r < 4; r++){
          const int i = i0 + r;
          const int b = i >> 11, s = i & 2047;
          O[((size_t)(b * H_ + h) * S_ + s) * D_ + d] = f2bf(acc[mf][nf][r]);
        }
      }
    }
}

// ---------- in-place RoPE on Q and K ----------
__global__ void rope_k(unsigned short* __restrict__ Q, unsigned short* __restrict__ K,
                       const float* __restrict__ ctab, const float* __restrict__ stab){
  int idx = blockIdx.x * 256 + threadIdx.x;
  unsigned short* P = (idx >= (1 << 20)) ? K : Q;
  int e  = idx & ((1 << 20) - 1);
  int g  = e & 15;
  int s  = (e >> 4) & 2047;
  int bh = e >> 15;
  int d0 = g * 4;
  size_t base = ((size_t)bh * S_ + s) * D_;
  us4 qa = *(us4*)(P + base + d0);
  us4 qb = *(us4*)(P + base + d0 + 64);
  fl4 ca = *(const fl4*)(ctab + s * D_ + d0);
  fl4 sa = *(const fl4*)(stab + s * D_ + d0);
  fl4 cb = *(const fl4*)(ctab + s * D_ + d0 + 64);
  fl4 sb = *(const fl4*)(stab + s * D_ + d0 + 64);
  us4 oa, ob;
  #pragma unroll
  for (int t = 0; t < 4; t++){
    float xa = bf2f(qa[t]), xb = bf2f(qb[t]);
    oa[t] = f2bf(xa * ca[t] - xb * sa[t]);
    ob[t] = f2bf(xb * cb[t] + xa * sb[t]);
  }
  *(us4*)(P + base + d0)      = oa;
  *(us4*)(P + base + d0 + 64) = ob;
}

// ---------- flash attention (R4-proven): 4 waves, QBLK=64, dbuf g2lds ----------
__global__ __launch_bounds__(256) void attn_k(
    const unsigned short* __restrict__ Q,
    const unsigned short* __restrict__ Kg,
    const unsigned short* __restrict__ Vt,
    const float* __restrict__ mask,
    const float* __restrict__ alibi,
    unsigned short* __restrict__ Ctx)
{
  __shared__ __align__(16) unsigned short Kl[2][64 * 128];
  __shared__ __align__(16) unsigned short Vl[2][128 * 64];
  const int tid = threadIdx.x;
  const int l = tid & 63, lg = l >> 4, lr = l & 15;
  const int w = tid >> 6;
  const int bh = blockIdx.y, b = bh >> 4, h = bh & 15;
  const int q0 = blockIdx.x * 64 + w * 16;
  const size_t hb = (size_t)bh * S_ * D_;
  const float* mrow = mask + (size_t)(q0 + lr) * S_;
  const float* al = alibi + h * S_;
  const int sidx = (l & 48) + ((l & 48) >> 2);
  const float SCL2E = 0.08838834764831845f * 1.4426950408889634f;
  const float L2E = 1.4426950408889634f;

  const int kswz = (((tid & 15) ^ ((tid >> 4) & 7)) * 8);
  const unsigned short* gK = Kg + hb + (size_t)(tid >> 4) * D_ + kswz;
  const int vswz = (((tid & 7) ^ ((tid >> 3) & 7)) * 8);
  const unsigned short* gV = Vt + hb + (size_t)(tid >> 3) * S_ + vswz;

  #define ASTAGE(buf, kv)  do {                                            \
    g2lds16(gK + (size_t)((kv))      * D_, Kl[buf] + tid * 8);             \
    g2lds16(gK + (size_t)((kv) + 16) * D_, Kl[buf] + 2048 + tid * 8);      \
    g2lds16(gK + (size_t)((kv) + 32) * D_, Kl[buf] + 4096 + tid * 8);      \
    g2lds16(gK + (size_t)((kv) + 48) * D_, Kl[buf] + 6144 + tid * 8);      \
    g2lds16(gV + (kv),                     Vl[buf] + tid * 8);             \
    g2lds16(gV + 32 * S_ + (kv),           Vl[buf] + 2048 + tid * 8);      \
    g2lds16(gV + 64 * S_ + (kv),           Vl[buf] + 4096 + tid * 8);      \
    g2lds16(gV + 96 * S_ + (kv),           Vl[buf] + 6144 + tid * 8);      \
  } while (0)

  int koff[4];
  #pragma unroll
  for (int c = 0; c < 4; c++) koff[c] = ((c * 4 + lg) ^ (lr & 7)) * 8;
  const int vo0 = (lg ^ (lr & 7)) * 8, vo1 = ((4 + lg) ^ (lr & 7)) * 8;

  short8 qf[4];
  #pragma unroll
  for (int c = 0; c < 4; c++)
    qf[c] = *(const short8*)(Q + hb + (size_t)(q0 + lr) * D_ + c * 32 + lg * 8);

  f32x4 acc[8];
  #pragma unroll
  for (int c = 0; c < 8; c++) acc[c] = f32x4{0.f, 0.f, 0.f, 0.f};
  float mr = -1e30f, lsum = 0.f;

  ASTAGE(0, 0);
  __syncthreads();
  int cur = 0;

  for (int t = 0; t < 32; t++){
    const int kv0 = t * 64;
    if (t < 31) ASTAGE(cur ^ 1, kv0 + 64);

    fl4 mk[4], aa[4];
    #pragma unroll
    for (int g = 0; g < 4; g++){
      mk[g] = *(const fl4*)(mrow + kv0 + g * 16 + 4 * lg);
      aa[g] = *(const fl4*)(al  + kv0 + g * 16 + 4 * lg);
    }

    f32x4 sg[4];
    #pragma unroll
    for (int g = 0; g < 4; g++) sg[g] = f32x4{0.f, 0.f, 0.f, 0.f};
    #pragma unroll
    for (int g = 0; g < 4; g++){
      const int row = g * 16 + lr;
      #pragma unroll
      for (int c = 0; c < 4; c++){
        short8 kf = *(const short8*)(Kl[cur] + row * 128 + koff[c]);
        sg[g] = __builtin_amdgcn_mfma_f32_16x16x32_bf16(kf, qf[c], sg[g], 0, 0, 0);
      }
    }

    float x[4][4];
    #pragma unroll
    for (int g = 0; g < 4; g++)
      #pragma unroll
      for (int r = 0; r < 4; r++)
        x[g][r] = fmaf(sg[g][r], SCL2E, (mk[g][r] + aa[g][r]) * L2E);

    float mx = -1e30f;
    #pragma unroll
    for (int g = 0; g < 4; g++)
      #pragma unroll
      for (int r = 0; r < 4; r++) mx = fmaxf(mx, x[g][r]);

    float p[4][4], ps = 0.f;
    if (__all(mx <= mr + 8.f)){
      #pragma unroll
      for (int g = 0; g < 4; g++)
        #pragma unroll
        for (int r = 0; r < 4; r++){
          p[g][r] = exp2f(x[g][r] - mr);
          ps += p[g][r];
        }
      ps += __shfl_xor(ps, 16);
      ps += __shfl_xor(ps, 32);
      lsum += ps;
    } else {
      mx = fmaxf(mx, __shfl_xor(mx, 16));
      mx = fmaxf(mx, __shfl_xor(mx, 32));
      float mnew = fmaxf(mr, mx);
      float alpha = exp2f(mr - mnew);
      #pragma unroll
      for (int g = 0; g < 4; g++)
        #pragma unroll
        for (int r = 0; r < 4; r++){
          p[g][r] = exp2f(x[g][r] - mnew);
          ps += p[g][r];
        }
      ps += __shfl_xor(ps, 16);
      ps += __shfl_xor(ps, 32);
      lsum = lsum * alpha + ps;
      mr = mnew;
      float ar[4];
      #pragma unroll
      for (int r = 0; r < 4; r++) ar[r] = __shfl(alpha, sidx + r);
      #pragma unroll
      for (int c = 0; c < 8; c++)
        #pragma unroll
        for (int r = 0; r < 4; r++) acc[c][r] *= ar[r];
    }

    int pk0[4], pk1[4];
    #pragma unroll
    for (int r = 0; r < 4; r++){
      pk0[r] = cvtpk(p[0][r], p[1][r]);
      pk1[r] = cvtpk(p[2][r], p[3][r]);
    }

    const int srcb = lr + ((lg & 1) << 5);
    short8 af0, af1;
    #pragma unroll
    for (int j = 0; j < 8; j++){
      int w0 = __shfl(pk0[j & 3], srcb + ((j >> 2) << 4));
      int w1 = __shfl(pk1[j & 3], srcb + ((j >> 2) << 4));
      af0[j] = (short)((l & 32) ? ((unsigned)w0 >> 16) : ((unsigned)w0 & 0xffffu));
      af1[j] = (short)((l & 32) ? ((unsigned)w1 >> 16) : ((unsigned)w1 & 0xffffu));
    }

    #pragma unroll
    for (int c = 0; c < 8; c++){
      const int d0 = c * 16 + lr;
      short8 vf0 = *(const short8*)(Vl[cur] + d0 * 64 + vo0);
      short8 vf1 = *(const short8*)(Vl[cur] + d0 * 64 + vo1);
      acc[c] = __builtin_amdgcn_mfma_f32_16x16x32_bf16(af0, vf0, acc[c], 0, 0, 0);
      acc[c] = __builtin_amdgcn_mfma_f32_16x16x32_bf16(af1, vf1, acc[c], 0, 0, 0);
    }

    __syncthreads();
    cur ^= 1;
  }
  #undef ASTAGE

  float inv = 1.f / lsum;
  float ir[4];
  #pragma unroll
  for (int r = 0; r < 4; r++) ir[r] = __shfl(inv, sidx + r);
  #pragma unroll
  for (int r = 0; r < 4; r++){
    const int qg = q0 + 4 * lg + r;
    const size_t ob = ((size_t)(b * S_ + qg) * H_ + h) * D_;
    #pragma unroll
    for (int c = 0; c < 8; c++)
      Ctx[ob + c * 16 + lr] = f2bf(acc[c][r] * ir[r]);
  }
}

extern "C" void kernel_launch(void* const* d_in, const int* in_sizes, int n_in,
                              void* d_out, int out_size, void* d_ws, size_t ws_size,
                              hipStream_t stream){
  const float* x     = (const float*)d_in[0];
  const float* mask  = (const float*)d_in[1];
  const float* alibi = (const float*)d_in[2];
  const float* freqs = (const float*)d_in[3];
  const float* Wq    = (const float*)d_in[4];
  const float* Wk    = (const float*)d_in[5];
  const float* Wv    = (const float*)d_in[6];
  const float* Wo    = (const float*)d_in[7];
  float* out = (float*)d_out;

  unsigned short* ws  = (unsigned short*)d_ws;
  unsigned short* xb  = ws;
  unsigned short* wqb = ws + 8388608;
  unsigned short* wkb = ws + 12582912;
  unsigned short* wvb = ws + 16777216;
  unsigned short* wob = ws + 20971520;
  unsigned short* Qb  = ws + 25165824;
  unsigned short* Kb  = ws + 33554432;
  unsigned short* Vb  = ws + 41943040;         // V^T [B,H,D,S]
  unsigned short* ctx = xb;
  float* ctab = (float*)(ws + 50331648);
  float* stab = ctab + 262144;

  cvt_k<<<8192, 256, 0, stream>>>(x,  xb);
  cvt_k<<<4096, 256, 0, stream>>>(Wq, wqb);
  cvt_k<<<4096, 256, 0, stream>>>(Wk, wkb);
  cvt_k<<<4096, 256, 0, stream>>>(Wv, wvb);
  cvt_k<<<4096, 256, 0, stream>>>(Wo, wob);
  tab_k<<<1024, 256, 0, stream>>>(freqs, ctab, stab);

  gemm8_k<1><<<dim3(16, 8, 3), 512, 0, stream>>>(xb, wqb, wkb, wvb,
                                                 Qb, Kb, Vb, nullptr);
  rope_k<<<8192, 256, 0, stream>>>(Qb, Kb, ctab, stab);
  attn_k<<<dim3(32, 32), 256, 0, stream>>>(Qb, Kb, Vb, mask, alibi, ctx);
  gemm8_k<0><<<dim3(16, 8, 1), 512, 0, stream>>>(ctx, wob, nullptr, nullptr,
                                                 nullptr, nullptr, nullptr, out);
}